// Round 9
// baseline (49.934 us; speedup 1.0000x reference)
//
#include <hip/hip_runtime.h>
#include <hip/hip_bf16.h>

// Q8_0-style fused dequant + linear: y[32,11008] = x[32,4096] @ W^T + bias
// W[o,i] = (qweight[o,i] - 127) * scales[o, i/32]
//
// Round 9: linear-burst W staging via global_load_lds.
//  - Block = 64 o x 32 m x KT=128 k (NSPLIT=32, split-major grid, 5504 blocks).
//  - W: per wave 8x global_load_lds_dwordx4, each a 1 KB contiguous burst
//    (2 rows x 512 B) -> raw int32 tile in LDS. Global source is
//    inverse-XOR-swizzled per lane; LDS dest linear; reads re-apply the XOR
//    (both-sides-or-neither rule) -> conflict-free ds_read_b128.
//  - One __syncthreads (vmcnt(0) drain == stage completion), then pure
//    LDS->dequant->MFMA compute. No inner barriers, no atomics.
//  - LDS = 32KB W + 8KB x = 40960 B -> exactly 4 blocks/CU; stage of one
//    block overlaps compute of the other three.
//  - Partials: f16 [split][o][m], packed uint2 stores (round-8 scheme, proven).

#define O_DIM  11008
#define I_DIM  4096
#define NB     128                // scale blocks per o-row
#define B_DIM  32
#define NSPLIT 32
#define KT     (I_DIM / NSPLIT)   // 128 ints per row per split
#define PART_STRIDE (O_DIM * B_DIM)   // ushorts per split partial, layout [o][m]

typedef __attribute__((ext_vector_type(8))) short bf16x8;
typedef __attribute__((ext_vector_type(8))) unsigned short u16x8;
typedef __attribute__((ext_vector_type(4))) float f32x4;
typedef __attribute__((ext_vector_type(4))) int   i32x4;

static __device__ __forceinline__ unsigned short f2bf(float f) {
    return __builtin_bit_cast(unsigned short, __float2bfloat16(f));
}

static __device__ __forceinline__ unsigned int pkf16(float a, float b) {
    const unsigned short ua = __builtin_bit_cast(unsigned short, (_Float16)a);
    const unsigned short ub = __builtin_bit_cast(unsigned short, (_Float16)b);
    return (unsigned int)ua | ((unsigned int)ub << 16);
}

static __device__ __forceinline__ void gl_lds16(const void* g, void* l) {
    __builtin_amdgcn_global_load_lds(
        (const __attribute__((address_space(1))) void*)g,
        (__attribute__((address_space(3))) void*)l,
        16, 0, 0);
}

static __device__ __forceinline__ bf16x8 dequant8(const i32x4 qa, const i32x4 qb,
                                                  const float s) {
    const float c = -127.0f * s;
    bf16x8 v;
    v[0] = (short)f2bf(fmaf((float)qa[0], s, c));
    v[1] = (short)f2bf(fmaf((float)qa[1], s, c));
    v[2] = (short)f2bf(fmaf((float)qa[2], s, c));
    v[3] = (short)f2bf(fmaf((float)qa[3], s, c));
    v[4] = (short)f2bf(fmaf((float)qb[0], s, c));
    v[5] = (short)f2bf(fmaf((float)qb[1], s, c));
    v[6] = (short)f2bf(fmaf((float)qb[2], s, c));
    v[7] = (short)f2bf(fmaf((float)qb[3], s, c));
    return v;
}

__global__ __launch_bounds__(256) void gemm_kernel(const float* __restrict__ x,
                                                   const int*   __restrict__ qw,
                                                   const float* __restrict__ scales,
                                                   unsigned short* __restrict__ part) {
    __shared__ int            w_s[64 * KT];        // 32 KB raw int32 quants
    __shared__ unsigned short x_s[B_DIM * KT];     // 8 KB bf16, XOR-swizzled

    const int t    = threadIdx.x;
    const int wav  = t >> 6;
    const int lan  = t & 63;
    const int lrow = lan & 15;      // fragment row (o within wave tile)
    const int lq   = lan >> 4;      // lane quarter -> k sub-offset

    const int split  = blockIdx.x;                 // fastest-varying: k-split
    const int k_base = split * KT;
    const int o_wave = blockIdx.y * 64 + wav * 16;
    const int o_row  = o_wave + lrow;

    // ---- issue W stage first: 8 x global_load_lds (1 KB linear burst each;
    //      instruction j covers rows 2j (lanes 0-31) and 2j+1 (lanes 32-63)).
    //      Global source pre-swizzled so that swizzled LDS reads see row-linear
    //      data: LDS[rl*512 + s] = W[rl][s ^ ((rl&7)<<4)].
    {
        const int  half = lan >> 5;                // 0|1 -> which row of the pair
        const int  li   = lan & 31;                // 16B slot within the row
        char*       ldsb = (char*)w_s + wav * 8192;
        const char* gb   = (const char*)(qw + (size_t)o_wave * I_DIM + k_base);
#pragma unroll
        for (int j = 0; j < 8; ++j) {
            const int rl  = 2 * j + half;
            const int off = (li * 16) ^ ((rl & 7) << 4);
            gl_lds16(gb + (size_t)rl * (I_DIM * 4) + off, ldsb + j * 1024);
        }
    }

    // ---- scales: 4 per lane (this row's 4 k-steps of 32) ----
    const float4 scv = *reinterpret_cast<const float4*>(&scales[o_row * NB + split * 4]);
    const float sc[4] = {scv.x, scv.y, scv.z, scv.w};

    // ---- stage x: f32 global -> bf16 swizzled LDS (overlaps W latency) ----
    {
        const int m  = t >> 3;            // 0..31
        const int k0 = (t & 7) * 16;      // 0..112
        const float4* xv = reinterpret_cast<const float4*>(x + m * I_DIM + k_base + k0);
#pragma unroll
        for (int j = 0; j < 2; ++j) {
            const float4 va = xv[2 * j];
            const float4 vb = xv[2 * j + 1];
            bf16x8 v;
            v[0] = (short)f2bf(va.x); v[1] = (short)f2bf(va.y);
            v[2] = (short)f2bf(va.z); v[3] = (short)f2bf(va.w);
            v[4] = (short)f2bf(vb.x); v[5] = (short)f2bf(vb.y);
            v[6] = (short)f2bf(vb.z); v[7] = (short)f2bf(vb.w);
            const int addr = ((m * KT + k0 + j * 8) * 2) ^ ((m & 7) << 4);
            *reinterpret_cast<bf16x8*>(reinterpret_cast<char*>(x_s) + addr) = v;
        }
    }

    // single barrier: compiler's vmcnt(0)+lgkmcnt(0) drain before s_barrier is
    // exactly the completion wait for global_load_lds + x ds_writes.
    __syncthreads();

    f32x4 acc0 = {0.f, 0.f, 0.f, 0.f};   // m rows 0..15
    f32x4 acc1 = {0.f, 0.f, 0.f, 0.f};   // m rows 16..31
    const int swz = (lrow & 7) << 4;      // same XOR for W rows and x rows
    const char* wbase = (const char*)w_s + wav * 8192 + lrow * 512;
    const char* xbase = (const char*)x_s;

#pragma unroll
    for (int ks = 0; ks < 4; ++ks) {
        const int off = ks * 128 + lq * 32;            // byte offset within W row
        const i32x4 qlo = *reinterpret_cast<const i32x4*>(wbase + ((off)      ^ swz));
        const i32x4 qhi = *reinterpret_cast<const i32x4*>(wbase + ((off + 16) ^ swz));
        const int kb2 = (ks * 32 + lq * 8) * 2;        // byte offset within x row
        const bf16x8 a0 = *reinterpret_cast<const bf16x8*>(
            xbase + (( lrow       * 256 + kb2) ^ swz));
        const bf16x8 a1 = *reinterpret_cast<const bf16x8*>(
            xbase + (((lrow + 16) * 256 + kb2) ^ swz));
        const bf16x8 bf = dequant8(qlo, qhi, sc[ks]);
        acc0 = __builtin_amdgcn_mfma_f32_16x16x32_bf16(a0, bf, acc0, 0, 0, 0);
        acc1 = __builtin_amdgcn_mfma_f32_16x16x32_bf16(a1, bf, acc1, 0, 0, 0);
    }

    // ---- epilogue: f16 partials, [split][o][m], 8-byte packed stores ----
    // C/D layout: col(o) = lane&15, row(m) = lq*4 + reg (acc0), +16 (acc1) [m89]
    unsigned short* pp = part + (size_t)split * PART_STRIDE + o_row * B_DIM;
    const uint2 v0 = make_uint2(pkf16(acc0[0], acc0[1]), pkf16(acc0[2], acc0[3]));
    const uint2 v1 = make_uint2(pkf16(acc1[0], acc1[1]), pkf16(acc1[2], acc1[3]));
    *reinterpret_cast<uint2*>(&pp[lq * 4])      = v0;
    *reinterpret_cast<uint2*>(&pp[16 + lq * 4]) = v1;
}

// ---- k2: thread-per-o reduce: out[m][o] = bias[o] + sum_s part[s][o][m] ----
__global__ __launch_bounds__(256) void reduce_kernel(const unsigned short* __restrict__ part,
                                                     const float* __restrict__ bias,
                                                     float* __restrict__ out) {
    const int o = blockIdx.x * 256 + threadIdx.x;   // 43 blocks = 11008 threads
    float v[B_DIM];
#pragma unroll
    for (int m = 0; m < B_DIM; ++m) v[m] = 0.f;

    for (int s = 0; s < NSPLIT; ++s) {
        const unsigned short* ps = part + (size_t)s * PART_STRIDE + o * B_DIM;
#pragma unroll
        for (int g = 0; g < 4; ++g) {
            const u16x8 p = *reinterpret_cast<const u16x8*>(ps + g * 8);
#pragma unroll
            for (int j = 0; j < 8; ++j)
                v[g * 8 + j] += (float)__builtin_bit_cast(_Float16, (unsigned short)p[j]);
        }
    }

    const float b = bias[o];
#pragma unroll
    for (int m = 0; m < B_DIM; ++m)
        out[m * O_DIM + o] = v[m] + b;
}

extern "C" void kernel_launch(void* const* d_in, const int* in_sizes, int n_in,
                              void* d_out, int out_size, void* d_ws, size_t ws_size,
                              hipStream_t stream) {
    const float* x      = (const float*)d_in[0];
    const int*   qw     = (const int*)d_in[1];
    const float* scales = (const float*)d_in[2];
    const float* bias   = (const float*)d_in[3];
    float*       out    = (float*)d_out;
    unsigned short* part = (unsigned short*)d_ws;    // 32 x 11008 x 32 f16 = 22.5 MB

    // k1: linear-burst staged dequant-MFMA GEMM, split-major dispatch
    hipLaunchKernelGGL(gemm_kernel, dim3(NSPLIT, O_DIM / 64), dim3(256), 0, stream,
                       x, qw, scales, part);

    // k2: reduce partials + bias
    hipLaunchKernelGGL(reduce_kernel, dim3(O_DIM / 256), dim3(256), 0, stream,
                       part, bias, out);
}

// Round 10
// 49.496 us; speedup vs baseline: 1.0088x; 1.0088x over previous
//
#include <hip/hip_runtime.h>
#include <hip/hip_bf16.h>

// Q8_0-style fused dequant + linear: y[32,11008] = x[32,4096] @ W^T + bias
// W[o,i] = (qweight[o,i] - 127) * scales[o, i/32]
//
// Round 10: barrier-free counted-vmcnt pipeline (never drain to 0).
//  - 1 wave = 1 item = 16 o-rows x 512 k. 5504 items = 2752 blocks x 2 waves
//    (exact static balance). No __syncthreads anywhere in the GEMM.
//  - W: per sub-chunk (128 k) one pinned group of 8 global_load_lds 1KB bursts
//    into a wave-private 2x8KB LDS ring. Manual s_waitcnt vmcnt(8) keeps the
//    newest group always in flight; lgkmcnt(0) fences the ring WAR.
//    Global source XOR-pre-swizzled / reads XOR-swizzled (round-9-proven
//    involution) -> 2-way-max bank conflicts on ds_read_b128.
//  - x frags in registers (two named sets, loads pinned between groups so
//    the manual vmcnt counts stay exact under any scheduling).
//  - steady outstanding ~8-16KB/wave x 10 waves/CU >> 22KB/CU needed for 6TB/s.
//  - Epilogue: f16 partials [sg][o][m] packed uint2 (round-8 proven), NSG=8.

#define O_DIM  11008
#define I_DIM  4096
#define NB     128
#define B_DIM  32
#define NSG    8                       // split-groups of 512 k
#define PART_STRIDE (O_DIM * B_DIM)    // ushorts per group partial, layout [o][m]

typedef __attribute__((ext_vector_type(8))) short bf16x8;
typedef __attribute__((ext_vector_type(8))) unsigned short u16x8;
typedef __attribute__((ext_vector_type(4))) float f32x4;
typedef __attribute__((ext_vector_type(4))) int   i32x4;

static __device__ __forceinline__ unsigned short f2bf(float f) {
    return __builtin_bit_cast(unsigned short, __float2bfloat16(f));
}
static __device__ __forceinline__ unsigned int pkf16(float a, float b) {
    const unsigned short ua = __builtin_bit_cast(unsigned short, (_Float16)a);
    const unsigned short ub = __builtin_bit_cast(unsigned short, (_Float16)b);
    return (unsigned int)ua | ((unsigned int)ub << 16);
}
static __device__ __forceinline__ void gl_lds16(const void* g, void* l) {
    __builtin_amdgcn_global_load_lds(
        (const __attribute__((address_space(1))) void*)g,
        (__attribute__((address_space(3))) void*)l,
        16, 0, 0);
}
static __device__ __forceinline__ bf16x8 dequant8(const i32x4 qa, const i32x4 qb,
                                                  const float s) {
    const float c = -127.0f * s;
    bf16x8 v;
    v[0] = (short)f2bf(fmaf((float)qa[0], s, c));
    v[1] = (short)f2bf(fmaf((float)qa[1], s, c));
    v[2] = (short)f2bf(fmaf((float)qa[2], s, c));
    v[3] = (short)f2bf(fmaf((float)qa[3], s, c));
    v[4] = (short)f2bf(fmaf((float)qb[0], s, c));
    v[5] = (short)f2bf(fmaf((float)qb[1], s, c));
    v[6] = (short)f2bf(fmaf((float)qb[2], s, c));
    v[7] = (short)f2bf(fmaf((float)qb[3], s, c));
    return v;
}

// ---- k1: x -> bf16 ----
__global__ __launch_bounds__(256) void convert_kernel(const float* __restrict__ x,
                                                      unsigned short* __restrict__ xbf) {
    const int gid = blockIdx.x * 256 + threadIdx.x;   // 128 blocks
    const float4 v = reinterpret_cast<const float4*>(x)[gid];
    ushort4 u;
    u.x = f2bf(v.x); u.y = f2bf(v.y); u.z = f2bf(v.z); u.w = f2bf(v.w);
    reinterpret_cast<ushort4*>(xbf)[gid] = u;
}

#define SBAR __builtin_amdgcn_sched_barrier(0)
#define WAITV8 { asm volatile("s_waitcnt vmcnt(8)" ::: "memory"); SBAR; }
#define WAITV0 { asm volatile("s_waitcnt vmcnt(0)" ::: "memory"); SBAR; }
#define WAITL  { asm volatile("s_waitcnt lgkmcnt(0)" ::: "memory"); SBAR; }

__global__ __launch_bounds__(128) void gemm_kernel(const unsigned short* __restrict__ xbf,
                                                   const int*   __restrict__ qw,
                                                   const float* __restrict__ scales,
                                                   unsigned short* __restrict__ part) {
    __shared__ int w_s[2][2][2048];   // [wave][ring buf][16 rows x 128 ints] = 32 KB

    const int t    = threadIdx.x;
    const int wav  = t >> 6;
    const int lan  = t & 63;
    const int lrow = lan & 15;      // fragment row (o)
    const int lq   = lan >> 4;      // lane quarter (k sub-offset)
    const int half = lan >> 5;      // staging: which row of the pair
    const int li   = lan & 31;      // staging: 16B slot in row

    const int item   = blockIdx.x * 2 + wav;   // 5504 items exactly
    const int o_tile = item >> 3;
    const int sg     = item & 7;
    const int o_base = o_tile * 16;
    const int o_row  = o_base + lrow;
    const int k0     = sg * 512;               // ints

    // ---- scales (16) + x-frag set 0: issued BEFORE any W stage group ----
    float sc[16];
    {
        const float4* sp = reinterpret_cast<const float4*>(&scales[o_row * NB + sg * 16]);
#pragma unroll
        for (int j = 0; j < 4; ++j) {
            const float4 v = sp[j];
            sc[4*j] = v.x; sc[4*j+1] = v.y; sc[4*j+2] = v.z; sc[4*j+3] = v.w;
        }
    }
    const unsigned short* xa = xbf + lrow * I_DIM + k0 + lq * 8;

    bf16x8 xe0,xe1,xe2,xe3,xe4,xe5,xe6,xe7;   // x frags, even sub-chunks
    bf16x8 xo0,xo1,xo2,xo3,xo4,xo5,xo6,xo7;   // x frags, odd sub-chunks

#define LOADX(P, c) { \
    const unsigned short* xp = xa + (c) * 128; \
    P##0 = *(const bf16x8*)(xp);       P##1 = *(const bf16x8*)(xp + 16*I_DIM); \
    P##2 = *(const bf16x8*)(xp + 32);  P##3 = *(const bf16x8*)(xp + 32 + 16*I_DIM); \
    P##4 = *(const bf16x8*)(xp + 64);  P##5 = *(const bf16x8*)(xp + 64 + 16*I_DIM); \
    P##6 = *(const bf16x8*)(xp + 96);  P##7 = *(const bf16x8*)(xp + 96 + 16*I_DIM); }

    const char* wsrc = (const char*)qw + ((size_t)o_base * I_DIM + k0) * 4;

    // one pinned stage group: 8 x 1KB bursts (rows 2j,2j+1 x 512 B), source
    // XOR-pre-swizzled so LDS[rl][b] = G[rl][b ^ ((rl&7)<<4)]
#define STAGE(c, buf) { SBAR; { \
    char* dst = (char*)&w_s[wav][buf][0]; \
    const char* src = wsrc + (c) * 512; \
    _Pragma("unroll") \
    for (int j = 0; j < 8; ++j) { \
        const int rl  = 2*j + half; \
        const int off = (li*16) ^ ((rl & 7) << 4); \
        gl_lds16(src + (size_t)rl * (I_DIM*4) + off, dst + j*1024); \
    } } SBAR; }

    i32x4 q0,q1,q2,q3,q4,q5,q6,q7;
    const int swz = (lrow & 7) << 4;

#define DSRD(buf) { \
    const char* rb = (const char*)&w_s[wav][buf][0] + lrow * 512; \
    q0 = *(const i32x4*)(rb + ((  0 + lq*32     ) ^ swz)); \
    q1 = *(const i32x4*)(rb + ((  0 + lq*32 + 16) ^ swz)); \
    q2 = *(const i32x4*)(rb + ((128 + lq*32     ) ^ swz)); \
    q3 = *(const i32x4*)(rb + ((128 + lq*32 + 16) ^ swz)); \
    q4 = *(const i32x4*)(rb + ((256 + lq*32     ) ^ swz)); \
    q5 = *(const i32x4*)(rb + ((256 + lq*32 + 16) ^ swz)); \
    q6 = *(const i32x4*)(rb + ((384 + lq*32     ) ^ swz)); \
    q7 = *(const i32x4*)(rb + ((384 + lq*32 + 16) ^ swz)); }

#define MFMA __builtin_amdgcn_mfma_f32_16x16x32_bf16
#define COMP(P, cc) { bf16x8 bb; \
    bb = dequant8(q0,q1,sc[(cc)*4+0]); acc0 = MFMA(P##0,bb,acc0,0,0,0); acc1 = MFMA(P##1,bb,acc1,0,0,0); \
    bb = dequant8(q2,q3,sc[(cc)*4+1]); acc0 = MFMA(P##2,bb,acc0,0,0,0); acc1 = MFMA(P##3,bb,acc1,0,0,0); \
    bb = dequant8(q4,q5,sc[(cc)*4+2]); acc0 = MFMA(P##4,bb,acc0,0,0,0); acc1 = MFMA(P##5,bb,acc1,0,0,0); \
    bb = dequant8(q6,q7,sc[(cc)*4+3]); acc0 = MFMA(P##6,bb,acc0,0,0,0); acc1 = MFMA(P##7,bb,acc1,0,0,0); }

    f32x4 acc0 = {0.f,0.f,0.f,0.f};   // m rows 0..15
    f32x4 acc1 = {0.f,0.f,0.f,0.f};   // m rows 16..31

    // ---- prologue: sc+x0 (oldest), then W0, W1; wait leaves W1 in flight ----
    LOADX(xe, 0)
    STAGE(0, 0)
    STAGE(1, 1)
    WAITV8                 // drains sc, x0, W0; W1 (newest 8) stays in flight
    // ---- c=0 ----
    LOADX(xo, 1)
    DSRD(0)
    WAITL                  // ring WAR fence: buf0 ds_reads retired
    STAGE(2, 0)
    COMP(xe, 0)
    WAITV8                 // drains x1, W1; W2 stays in flight
    // ---- c=1 ----
    LOADX(xe, 2)
    DSRD(1)
    WAITL
    STAGE(3, 1)
    COMP(xo, 1)
    WAITV8                 // drains x2, W2; W3 stays in flight
    // ---- c=2 ----
    LOADX(xo, 3)
    DSRD(0)
    COMP(xe, 2)
    WAITV0                 // tail: drain x3 + W3
    // ---- c=3 ----
    DSRD(1)
    COMP(xo, 3)

    // ---- epilogue: f16 partials [sg][o][m], packed 8-byte stores ----
    // C/D layout: col(o)=lane&15, row(m)=lq*4+reg (acc0), +16 (acc1)  [m89]
    unsigned short* pp = part + (size_t)sg * PART_STRIDE + (size_t)o_row * B_DIM;
    const uint2 v0 = make_uint2(pkf16(acc0[0],acc0[1]), pkf16(acc0[2],acc0[3]));
    const uint2 v1 = make_uint2(pkf16(acc1[0],acc1[1]), pkf16(acc1[2],acc1[3]));
    *reinterpret_cast<uint2*>(&pp[lq * 4])      = v0;
    *reinterpret_cast<uint2*>(&pp[16 + lq * 4]) = v1;
}

// ---- k3: thread-per-o reduce: out[m][o] = bias[o] + sum_g part[g][o][m] ----
__global__ __launch_bounds__(256) void reduce_kernel(const unsigned short* __restrict__ part,
                                                     const float* __restrict__ bias,
                                                     float* __restrict__ out) {
    const int o = blockIdx.x * 256 + threadIdx.x;   // 43 blocks = 11008 threads
    float v[B_DIM];
#pragma unroll
    for (int m = 0; m < B_DIM; ++m) v[m] = 0.f;

#pragma unroll
    for (int s = 0; s < NSG; ++s) {
        const unsigned short* ps = part + (size_t)s * PART_STRIDE + (size_t)o * B_DIM;
#pragma unroll
        for (int g = 0; g < 4; ++g) {
            const u16x8 p = *reinterpret_cast<const u16x8*>(ps + g * 8);
#pragma unroll
            for (int j = 0; j < 8; ++j)
                v[g * 8 + j] += (float)__builtin_bit_cast(_Float16, (unsigned short)p[j]);
        }
    }

    const float b = bias[o];
#pragma unroll
    for (int m = 0; m < B_DIM; ++m)
        out[m * O_DIM + o] = v[m] + b;
}

extern "C" void kernel_launch(void* const* d_in, const int* in_sizes, int n_in,
                              void* d_out, int out_size, void* d_ws, size_t ws_size,
                              hipStream_t stream) {
    const float* x      = (const float*)d_in[0];
    const int*   qw     = (const int*)d_in[1];
    const float* scales = (const float*)d_in[2];
    const float* bias   = (const float*)d_in[3];
    float*       out    = (float*)d_out;

    unsigned short* xbf  = (unsigned short*)d_ws;                 // 256 KB
    unsigned short* part = (unsigned short*)((char*)d_ws + 262144); // 5.64 MB

    // k1: x -> bf16
    hipLaunchKernelGGL(convert_kernel, dim3(128), dim3(256), 0, stream, x, xbf);

    // k2: barrier-free counted-vmcnt dequant-MFMA GEMM
    hipLaunchKernelGGL(gemm_kernel, dim3(2752), dim3(128), 0, stream,
                       xbf, qw, scales, part);

    // k3: reduce partials + bias
    hipLaunchKernelGGL(reduce_kernel, dim3(O_DIM / 256), dim3(256), 0, stream,
                       part, bias, out);
}